// Round 1
// baseline (762.898 us; speedup 1.0000x reference)
//
#include <hip/hip_runtime.h>
#include <hip/hip_bf16.h>
#include <cstdint>
#include <cstddef>

// Problem constants (B,C,H,W)=(2,128,192,192), K=4, O=60
constexpr int kB = 2, kC = 128, kH = 192, kW = 192, kK = 4, kO = 60;
constexpr int kHW  = kH * kW;        // 36864
constexpr int NPIX = kB * kHW;       // 73728
constexpr int MT   = 32;             // pixels per chain tile
constexpr float kSlope = 0.01f;

// ws layout (ints): [0..3]=bucket counters, [4]=flag_f32, [5]=flag_seg64,
// [64..64+4*NPIX)=buckets (pixel indices per k)

// ---------------- dtype helpers ----------------
__device__ __forceinline__ float load1(const float* p) { return *p; }
__device__ __forceinline__ float load1(const __hip_bfloat16* p) {
  unsigned short u = *reinterpret_cast<const unsigned short*>(p);
  return __uint_as_float(((unsigned)u) << 16);
}
__device__ __forceinline__ void load4f(const float* p, float* o) {
  const float4 v = *reinterpret_cast<const float4*>(p);
  o[0] = v.x; o[1] = v.y; o[2] = v.z; o[3] = v.w;
}
__device__ __forceinline__ void load4f(const __hip_bfloat16* p, float* o) {
  union { short4 s; unsigned short u[4]; } v;
  v.s = *reinterpret_cast<const short4*>(p);
#pragma unroll
  for (int j = 0; j < 4; ++j) o[j] = __uint_as_float(((unsigned)v.u[j]) << 16);
}
__device__ __forceinline__ void store1(float* p, float v) { *p = v; }
__device__ __forceinline__ void store1(__hip_bfloat16* p, float v) { *p = __float2bfloat16(v); }

// ---------------- kernel 1: init + dtype sniff ----------------
__global__ void init_sniff(const void* xraw, const void* segraw, int* wsI) {
  __shared__ int s_bad, s_zero_even, s_odd_nz;
  const int tid = threadIdx.x;
  if (tid == 0) { s_bad = 0; s_zero_even = 0; s_odd_nz = 0; }
  __syncthreads();

  // Sniff fusion_context: interpret first 4096 16-bit halves as bf16.
  // f32 data -> low-mantissa halves look like absurd bf16 exponents.
  // f32 storing bf16-rounded values -> low halves are all zero.
  const unsigned short* hx = (const unsigned short*)xraw;
  int bad = 0, zev = 0;
#pragma unroll
  for (int j = 0; j < 16; ++j) {
    const int idx = tid * 16 + j;               // 0..4095
    const unsigned short h = hx[idx];
    const int e = (h >> 7) & 0xFF;
    if (e >= 0x84) bad++;                       // |x| >= 32: impossible for N(0,1) bf16
    if (((idx & 1) == 0) && h == 0) zev++;
  }
  // Sniff seg: int64 -> odd 32-bit words are all zero (values 0..3).
  const unsigned int* sw = (const unsigned int*)segraw;
  int onz = 0;
#pragma unroll
  for (int j = 0; j < 8; ++j) {
    const int idx = tid * 8 + j;                // 0..2047
    if ((idx & 1) == 1 && sw[idx] != 0) onz++;
  }
  atomicAdd(&s_bad, bad);
  atomicAdd(&s_zero_even, zev);
  atomicAdd(&s_odd_nz, onz);
  __syncthreads();
  if (tid == 0) {
    wsI[0] = 0; wsI[1] = 0; wsI[2] = 0; wsI[3] = 0;
    wsI[4] = (s_bad > 64 || s_zero_even > 1536) ? 1 : 0;  // 1 => f32 I/O
    wsI[5] = (s_odd_nz < 8) ? 1 : 0;                      // 1 => seg is int64
  }
}

// ---------------- kernel 2: bucket pixels by k ----------------
__global__ void compact_kernel(const void* segraw, int* wsI) {
  int* cnt = wsI;
  int* bucket = wsI + 64;
  const int flag64 = wsI[5];
  const int p = blockIdx.x * 256 + threadIdx.x;   // NPIX = 288*256 exactly
  int k;
  if (flag64) k = (int)((const long long*)segraw)[p];
  else        k = ((const int*)segraw)[p];

  __shared__ int lcnt[kK], lbase[kK];
  if (threadIdx.x < kK) lcnt[threadIdx.x] = 0;
  __syncthreads();
  const int li = atomicAdd(&lcnt[k], 1);
  __syncthreads();
  if (threadIdx.x < kK) lbase[threadIdx.x] = atomicAdd(&cnt[threadIdx.x], lcnt[threadIdx.x]);
  __syncthreads();
  bucket[k * NPIX + lbase[k] + li] = p;
}

// ---------------- layer: dst = op(W @ src + b [+ res]) ----------------
// src/dst/res are LDS [MT][kC]; W row-major [NOUT][kC] for fixed k.
template<typename T, int NOUT, bool LRELU, bool RES>
__device__ __forceinline__ void layer(const float (*src)[kC], float (*dst)[kC],
                                      const float (*res)[kC],
                                      const T* __restrict__ Wk,
                                      const T* __restrict__ bk, int tid) {
  const int og = tid & 31;       // 32 groups x 4 outputs = 128
  const int mg = tid >> 5;       // 8 groups x 4 pixels  = 32
  const int o0 = og * 4;
  const int m0 = mg * 4;
  if (o0 >= NOUT) return;

  float acc[4][4];
#pragma unroll
  for (int mi = 0; mi < 4; ++mi)
#pragma unroll
    for (int oi = 0; oi < 4; ++oi) acc[mi][oi] = 0.f;

  const T* w[4];
#pragma unroll
  for (int oi = 0; oi < 4; ++oi) w[oi] = Wk + (size_t)(o0 + oi) * kC;

#pragma unroll 2
  for (int c = 0; c < kC; c += 4) {
    float xv[4][4], wv[4][4];
#pragma unroll
    for (int mi = 0; mi < 4; ++mi) {
      const float4 v = *reinterpret_cast<const float4*>(&src[m0 + mi][c]);
      xv[mi][0] = v.x; xv[mi][1] = v.y; xv[mi][2] = v.z; xv[mi][3] = v.w;
    }
#pragma unroll
    for (int oi = 0; oi < 4; ++oi) load4f(w[oi] + c, wv[oi]);
#pragma unroll
    for (int mi = 0; mi < 4; ++mi)
#pragma unroll
      for (int oi = 0; oi < 4; ++oi)
#pragma unroll
        for (int j = 0; j < 4; ++j)
          acc[mi][oi] = fmaf(xv[mi][j], wv[oi][j], acc[mi][oi]);
  }

  float bias[4];
  load4f(bk + o0, bias);
#pragma unroll
  for (int mi = 0; mi < 4; ++mi) {
    float v[4];
#pragma unroll
    for (int oi = 0; oi < 4; ++oi) {
      float t = acc[mi][oi] + bias[oi];
      if constexpr (LRELU) t = (t >= 0.f) ? t : kSlope * t;
      v[oi] = t;
    }
    if constexpr (RES) {
      const float4 rv = *reinterpret_cast<const float4*>(&res[m0 + mi][o0]);
      v[0] += rv.x; v[1] += rv.y; v[2] += rv.z; v[3] += rv.w;
    }
    *reinterpret_cast<float4*>(&dst[m0 + mi][o0]) = make_float4(v[0], v[1], v[2], v[3]);
  }
}

// ---------------- kernel 3: per-bucket fused conv chain ----------------
template<typename T>
__device__ void chain_body(const T* __restrict__ x,
                           const T* __restrict__ W1, const T* __restrict__ b1,
                           const T* __restrict__ Wr1, const T* __restrict__ br1,
                           const T* __restrict__ Wr2, const T* __restrict__ br2,
                           const T* __restrict__ W3, const T* __restrict__ b3,
                           const T* __restrict__ W4, const T* __restrict__ b4,
                           T* __restrict__ out,
                           const int* cnt, const int* bucket,
                           float (*xa)[kC], float (*xb)[kC], float (*hres)[kC],
                           int* spix) {
  const int tid = threadIdx.x;

  // map blockIdx -> (k, tile start) from bucket counts
  int n[kK];
#pragma unroll
  for (int kk = 0; kk < kK; ++kk) n[kk] = cnt[kk];
  int k = -1, mstart = 0, accT = 0;
#pragma unroll
  for (int kk = 0; kk < kK; ++kk) {
    const int tk = (n[kk] + MT - 1) / MT;
    if (k < 0 && blockIdx.x < accT + tk) { k = kk; mstart = (blockIdx.x - accT) * MT; }
    accT += tk;
  }
  if (k < 0) return;
  const int nv = min(MT, n[k] - mstart);

  if (tid < nv) spix[tid] = bucket[k * NPIX + mstart + tid];
  __syncthreads();

  // gather x: lanes over pixels (bucketed pixels are spatially local)
  {
    const int i = tid & 31;
    const int cg = tid >> 5;           // 8 groups x 16 channels
    int b = 0, hw = 0, valid = (i < nv);
    if (valid) { const int p = spix[i]; b = p / kHW; hw = p - b * kHW; }
#pragma unroll
    for (int j = 0; j < 16; ++j) {
      const int c = cg * 16 + j;
      xa[i][c] = valid ? load1(x + ((size_t)b * kC + c) * kHW + hw) : 0.f;
    }
  }
  __syncthreads();

  const T* W1k  = W1  + (size_t)k * kC * kC;  const T* b1k  = b1  + (size_t)k * kC;
  const T* Wr1k = Wr1 + (size_t)k * kC * kC;  const T* br1k = br1 + (size_t)k * kC;
  const T* Wr2k = Wr2 + (size_t)k * kC * kC;  const T* br2k = br2 + (size_t)k * kC;
  const T* W3k  = W3  + (size_t)k * kC * kC;  const T* b3k  = b3  + (size_t)k * kC;
  const T* W4k  = W4  + (size_t)k * kO * kC;  const T* b4k  = b4  + (size_t)k * kO;

  layer<T, kC, false, false>(xa,   hres, xa,   W1k,  b1k,  tid); __syncthreads(); // h
  layer<T, kC, true,  false>(hres, xb,   xa,   Wr1k, br1k, tid); __syncthreads(); // lrelu(conv(h))
  layer<T, kC, false, true >(xb,   xa,   hres, Wr2k, br2k, tid); __syncthreads(); // h = h + r
  layer<T, kC, true,  false>(xa,   xb,   xa,   W3k,  b3k,  tid); __syncthreads(); // lrelu(conv)
  layer<T, kO, false, false>(xb,   xa,   xb,   W4k,  b4k,  tid); __syncthreads(); // conv_outs (60)

  // scatter out[b][o][hw]: lanes over pixels
  {
    const int i = tid & 31;
    const int ogr = tid >> 5;          // 8 groups x 8 outputs (>=60)
    if (i < nv) {
      const int p = spix[i];
      const int b = p / kHW;
      const int hw = p - b * kHW;
      T* obase = out + (size_t)b * kO * kHW + hw;
#pragma unroll
      for (int j = 0; j < 8; ++j) {
        const int o = ogr * 8 + j;
        if (o < kO) store1(obase + (size_t)o * kHW, xa[i][o]);
      }
    }
  }
}

__global__ __launch_bounds__(256, 3) void chain_kernel(
    const void* x, const void* W1, const void* b1, const void* Wr1, const void* br1,
    const void* Wr2, const void* br2, const void* W3, const void* b3,
    const void* W4, const void* b4, void* out, int* wsI) {
  __shared__ float xa[MT][kC];     // 16 KB
  __shared__ float xb[MT][kC];     // 16 KB
  __shared__ float hres[MT][kC];   // 16 KB
  __shared__ int spix[MT];
  const int* cnt = wsI;
  const int* bucket = wsI + 64;
  if (wsI[4]) {
    chain_body<float>((const float*)x,
                      (const float*)W1, (const float*)b1,
                      (const float*)Wr1, (const float*)br1,
                      (const float*)Wr2, (const float*)br2,
                      (const float*)W3, (const float*)b3,
                      (const float*)W4, (const float*)b4,
                      (float*)out, cnt, bucket, xa, xb, hres, spix);
  } else {
    chain_body<__hip_bfloat16>((const __hip_bfloat16*)x,
                               (const __hip_bfloat16*)W1, (const __hip_bfloat16*)b1,
                               (const __hip_bfloat16*)Wr1, (const __hip_bfloat16*)br1,
                               (const __hip_bfloat16*)Wr2, (const __hip_bfloat16*)br2,
                               (const __hip_bfloat16*)W3, (const __hip_bfloat16*)b3,
                               (const __hip_bfloat16*)W4, (const __hip_bfloat16*)b4,
                               (__hip_bfloat16*)out, cnt, bucket, xa, xb, hres, spix);
  }
}

extern "C" void kernel_launch(void* const* d_in, const int* in_sizes, int n_in,
                              void* d_out, int out_size, void* d_ws, size_t ws_size,
                              hipStream_t stream) {
  (void)in_sizes; (void)n_in; (void)out_size; (void)ws_size;
  int* wsI = (int*)d_ws;   // needs 256 B + 4*NPIX*4 B ≈ 1.13 MiB of ws
  init_sniff<<<1, 256, 0, stream>>>(d_in[0], d_in[1], wsI);
  compact_kernel<<<NPIX / 256, 256, 0, stream>>>(d_in[1], wsI);
  chain_kernel<<<NPIX / MT + kK, 256, 0, stream>>>(
      d_in[0], d_in[2], d_in[3], d_in[4], d_in[5], d_in[6], d_in[7],
      d_in[8], d_in[9], d_in[10], d_in[11], d_out, wsI);
}

// Round 3
// 225.185 us; speedup vs baseline: 3.3879x; 3.3879x over previous
//
#include <hip/hip_runtime.h>
#include <hip/hip_bf16.h>
#include <cstdint>
#include <cstddef>

// Problem constants (B,C,H,W)=(2,128,192,192), K=4, O=60
constexpr int kB = 2, kC = 128, kH = 192, kW = 192, kK = 4, kO = 60;
constexpr int kHW  = kH * kW;        // 36864
constexpr int NPIX = kB * kHW;       // 73728
constexpr int MT   = 32;             // pixels per chain tile
constexpr int LDA  = kC + 8;         // LDS row stride in bf16 elems (16B pad)
constexpr float kSlope = 0.01f;

// ws layout (ints): [0..3]=class totals, [4]=flag_f32, [5]=flag_seg64,
// [8 .. 8+288*4) = per-block per-class counts -> GLOBAL exclusive bases (after scan),
// [2048 .. 2048+NPIX) = flat sorted bucket (pixel indices, classes contiguous)
constexpr int WS_CNTS = 8;
constexpr int WS_BUCKET = 2048;
constexpr int NBLK = NPIX / 256;     // 288

typedef __attribute__((ext_vector_type(8))) short bf16x8;
typedef __attribute__((ext_vector_type(4))) float f32x4;

// ---------------- dtype helpers ----------------
__device__ __forceinline__ unsigned short f2bf(float f) {
  unsigned u = __float_as_uint(f);
  u += 0x7FFF + ((u >> 16) & 1);
  return (unsigned short)(u >> 16);
}
__device__ __forceinline__ float bf2f(unsigned short u) {
  return __uint_as_float(((unsigned)u) << 16);
}
__device__ __forceinline__ float load1(const float* p) { return *p; }
__device__ __forceinline__ float load1(const __hip_bfloat16* p) {
  return bf2f(*reinterpret_cast<const unsigned short*>(p));
}
__device__ __forceinline__ unsigned short loadbf(const __hip_bfloat16* p) {
  return *reinterpret_cast<const unsigned short*>(p);
}
__device__ __forceinline__ unsigned short loadbf(const float* p) { return f2bf(*p); }

__device__ __forceinline__ bf16x8 load_wfrag(const __hip_bfloat16* p) {
  return *reinterpret_cast<const bf16x8*>(p);
}
__device__ __forceinline__ bf16x8 load_wfrag(const float* p) {
  bf16x8 r;
#pragma unroll
  for (int j = 0; j < 8; ++j) r[j] = (short)f2bf(p[j]);
  return r;
}
__device__ __forceinline__ void store1(float* p, float v) { *p = v; }
__device__ __forceinline__ void store1(__hip_bfloat16* p, float v) {
  *reinterpret_cast<unsigned short*>(p) = f2bf(v);
}

// ---------------- kernel 1: dtype sniff ----------------
__global__ void init_sniff(const void* xraw, const void* segraw, int* wsI) {
  __shared__ int s_bad, s_zero_even, s_odd_nz;
  const int tid = threadIdx.x;
  if (tid == 0) { s_bad = 0; s_zero_even = 0; s_odd_nz = 0; }
  __syncthreads();
  const unsigned short* hx = (const unsigned short*)xraw;
  int bad = 0, zev = 0;
#pragma unroll
  for (int j = 0; j < 16; ++j) {
    const int idx = tid * 16 + j;
    const unsigned short h = hx[idx];
    const int e = (h >> 7) & 0xFF;
    if (e >= 0x84) bad++;                    // |x|>=32: impossible for N(0,1) bf16
    if (((idx & 1) == 0) && h == 0) zev++;
  }
  const unsigned int* sw = (const unsigned int*)segraw;
  int onz = 0;
#pragma unroll
  for (int j = 0; j < 8; ++j) {
    const int idx = tid * 8 + j;
    if ((idx & 1) == 1 && sw[idx] != 0) onz++;
  }
  atomicAdd(&s_bad, bad);
  atomicAdd(&s_zero_even, zev);
  atomicAdd(&s_odd_nz, onz);
  __syncthreads();
  if (tid == 0) {
    wsI[4] = (s_bad > 64 || s_zero_even > 1536) ? 1 : 0;  // 1 => f32 I/O
    wsI[5] = (s_odd_nz < 8) ? 1 : 0;                      // 1 => seg is int64
  }
}

// ---------------- sorted bucketing: count -> scan -> place ----------------
__global__ void count_kernel(const void* segraw, int* wsI) {
  __shared__ int lcnt[kK];
  if (threadIdx.x < kK) lcnt[threadIdx.x] = 0;
  __syncthreads();
  const int p = blockIdx.x * 256 + threadIdx.x;
  const int k = wsI[5] ? (int)((const long long*)segraw)[p]
                       : ((const int*)segraw)[p];
  atomicAdd(&lcnt[k], 1);
  __syncthreads();
  if (threadIdx.x < kK) wsI[WS_CNTS + blockIdx.x * kK + threadIdx.x] = lcnt[threadIdx.x];
}

__global__ void scan_kernel(int* wsI) {
  __shared__ int cnts[NBLK * kK];
  __shared__ int tot[kK], kbase[kK];
  const int tid = threadIdx.x;
  for (int i = tid; i < NBLK * kK; i += 256) cnts[i] = wsI[WS_CNTS + i];
  __syncthreads();
  if (tid < kK) {
    int s = 0;
    for (int b = 0; b < NBLK; ++b) s += cnts[b * kK + tid];
    tot[tid] = s;
  }
  __syncthreads();
  if (tid == 0) {
    int r = 0;
    for (int k = 0; k < kK; ++k) { kbase[k] = r; r += tot[k]; wsI[k] = tot[k]; }
  }
  __syncthreads();
  if (tid < kK) {
    int r = kbase[tid];   // GLOBAL exclusive base (flat bucket)
    for (int b = 0; b < NBLK; ++b) { int t = cnts[b * kK + tid]; cnts[b * kK + tid] = r; r += t; }
  }
  __syncthreads();
  for (int i = tid; i < NBLK * kK; i += 256) wsI[WS_CNTS + i] = cnts[i];
}

__global__ void place_kernel(const void* segraw, int* wsI) {
  __shared__ int lcnt[kK], lbase[kK];
  if (threadIdx.x < kK) {
    lcnt[threadIdx.x] = 0;
    lbase[threadIdx.x] = wsI[WS_CNTS + blockIdx.x * kK + threadIdx.x];
  }
  __syncthreads();
  const int p = blockIdx.x * 256 + threadIdx.x;
  const int k = wsI[5] ? (int)((const long long*)segraw)[p]
                       : ((const int*)segraw)[p];
  const int li = atomicAdd(&lcnt[k], 1);
  int* bucket = wsI + WS_BUCKET;
  bucket[lbase[k] + li] = p;        // FLAT global position (fix of R2 fault)
}

// ---------------- MFMA layer: dst = op(W @ src + b [+ res]) ----------------
// A-frag = weight rows (global, contiguous 16B): A[m=lane&15][k=quad*8+j]
// B-frag = activation rows (LDS, contiguous 16B): B[n=lane&15][k=quad*8+j]
// D: col=lane&15 (pixel), row=quad*4+reg (out channel)  [m89-verified mapping]
template<typename T, bool LRELU, bool RES>
__device__ __forceinline__ void layer128(const unsigned short (*src)[LDA],
                                         unsigned short (*dst)[LDA],
                                         const unsigned short (*res)[LDA],
                                         const T* __restrict__ Wk,
                                         const T* __restrict__ bk, int tid) {
  const int wave = tid >> 6, lane = tid & 63, quad = lane >> 4, col = lane & 15;
  bf16x8 a[2][4];
  float bias[2][4];
#pragma unroll
  for (int oi = 0; oi < 2; ++oi) {
    const int ot = wave * 2 + oi;
    const int row = ot * 16 + col;
#pragma unroll
    for (int ks = 0; ks < 4; ++ks)
      a[oi][ks] = load_wfrag(Wk + (size_t)row * kC + ks * 32 + quad * 8);
#pragma unroll
    for (int r = 0; r < 4; ++r) bias[oi][r] = load1(bk + ot * 16 + quad * 4 + r);
  }
#pragma unroll
  for (int pt = 0; pt < 2; ++pt) {
    const int pix = pt * 16 + col;
    bf16x8 b[4];
#pragma unroll
    for (int ks = 0; ks < 4; ++ks)
      b[ks] = *reinterpret_cast<const bf16x8*>(&src[pix][ks * 32 + quad * 8]);
#pragma unroll
    for (int oi = 0; oi < 2; ++oi) {
      f32x4 acc = {0.f, 0.f, 0.f, 0.f};
#pragma unroll
      for (int ks = 0; ks < 4; ++ks)
        acc = __builtin_amdgcn_mfma_f32_16x16x32_bf16(a[oi][ks], b[ks], acc, 0, 0, 0);
      const int nb = (wave * 2 + oi) * 16 + quad * 4;
      float v[4];
#pragma unroll
      for (int r = 0; r < 4; ++r) {
        float t = acc[r] + bias[oi][r];
        if constexpr (LRELU) t = (t >= 0.f) ? t : kSlope * t;
        v[r] = t;
      }
      if constexpr (RES) {
        const short4 rv = *reinterpret_cast<const short4*>(&res[pix][nb]);
        v[0] += bf2f((unsigned short)rv.x);
        v[1] += bf2f((unsigned short)rv.y);
        v[2] += bf2f((unsigned short)rv.z);
        v[3] += bf2f((unsigned short)rv.w);
      }
      short4 pk;
      pk.x = (short)f2bf(v[0]); pk.y = (short)f2bf(v[1]);
      pk.z = (short)f2bf(v[2]); pk.w = (short)f2bf(v[3]);
      *reinterpret_cast<short4*>(&dst[pix][nb]) = pk;
    }
  }
}

// last layer: NOUT=60, scatter to global
template<typename T>
__device__ __forceinline__ void layer_out(const unsigned short (*src)[LDA],
                                          const T* __restrict__ Wk,
                                          const T* __restrict__ bk,
                                          T* __restrict__ out,
                                          const int* spix, int nv, int tid) {
  const int wave = tid >> 6, lane = tid & 63, quad = lane >> 4, col = lane & 15;
  const int ot = wave;                         // 4 otiles cover 60 (last masked)
  bf16x8 a[4];
  const int row = min(ot * 16 + col, kO - 1);
#pragma unroll
  for (int ks = 0; ks < 4; ++ks)
    a[ks] = load_wfrag(Wk + (size_t)row * kC + ks * 32 + quad * 8);
  float bias[4];
#pragma unroll
  for (int r = 0; r < 4; ++r) {
    const int n = ot * 16 + quad * 4 + r;
    bias[r] = (n < kO) ? load1(bk + n) : 0.f;
  }
#pragma unroll
  for (int pt = 0; pt < 2; ++pt) {
    const int pix = pt * 16 + col;
    bf16x8 b[4];
#pragma unroll
    for (int ks = 0; ks < 4; ++ks)
      b[ks] = *reinterpret_cast<const bf16x8*>(&src[pix][ks * 32 + quad * 8]);
    f32x4 acc = {0.f, 0.f, 0.f, 0.f};
#pragma unroll
    for (int ks = 0; ks < 4; ++ks)
      acc = __builtin_amdgcn_mfma_f32_16x16x32_bf16(a[ks], b[ks], acc, 0, 0, 0);
    if (pix < nv) {
      const int p = spix[pix];
      const int bb = p / kHW;
      const int hw = p - bb * kHW;
      T* obase = out + (size_t)bb * kO * kHW + hw;
#pragma unroll
      for (int r = 0; r < 4; ++r) {
        const int n = ot * 16 + quad * 4 + r;
        if (n < kO) store1(obase + (size_t)n * kHW, acc[r] + bias[r]);
      }
    }
  }
}

// ---------------- chain: per-bucket fused conv chain ----------------
template<typename T>
__device__ void chain_body(const T* __restrict__ x,
                           const T* __restrict__ W1, const T* __restrict__ b1,
                           const T* __restrict__ Wr1, const T* __restrict__ br1,
                           const T* __restrict__ Wr2, const T* __restrict__ br2,
                           const T* __restrict__ W3, const T* __restrict__ b3,
                           const T* __restrict__ W4, const T* __restrict__ b4,
                           T* __restrict__ out, const int* cnt, const int* bucket,
                           unsigned short (*xa)[LDA], unsigned short (*xb)[LDA],
                           unsigned short (*hres)[LDA], int* spix) {
  const int tid = threadIdx.x;

  int n[kK];
#pragma unroll
  for (int kk = 0; kk < kK; ++kk) n[kk] = cnt[kk];
  // map blockIdx -> (k, tile start, flat class base)
  int k = -1, mstart = 0, accT = 0, kb = 0, pref = 0;
#pragma unroll
  for (int kk = 0; kk < kK; ++kk) {
    const int tk = (n[kk] + MT - 1) / MT;
    if (k < 0 && (int)blockIdx.x < accT + tk) {
      k = kk; mstart = ((int)blockIdx.x - accT) * MT; kb = pref;
    }
    accT += tk;
    pref += n[kk];
  }
  if (k < 0) return;
  const int nv = min(MT, n[k] - mstart);

  if (tid < nv) spix[tid] = bucket[kb + mstart + tid];   // flat bucket
  __syncthreads();

  // gather x -> bf16 LDS [pix][c]; zero-fill tail rows
  {
    const int i = tid & 31;
    const int cg = tid >> 5;
    const int valid = (i < nv);
    size_t base = 0;
    if (valid) {
      const int p = spix[i];
      const int bb = p / kHW;
      const int hw = p - bb * kHW;
      base = (size_t)bb * kC * kHW + hw;
    }
#pragma unroll
    for (int j = 0; j < 16; ++j) {
      const int c = cg * 16 + j;
      xa[i][c] = valid ? loadbf(x + base + (size_t)c * kHW) : (unsigned short)0;
    }
  }
  __syncthreads();

  const T* W1k  = W1  + (size_t)k * kC * kC;  const T* b1k  = b1  + (size_t)k * kC;
  const T* Wr1k = Wr1 + (size_t)k * kC * kC;  const T* br1k = br1 + (size_t)k * kC;
  const T* Wr2k = Wr2 + (size_t)k * kC * kC;  const T* br2k = br2 + (size_t)k * kC;
  const T* W3k  = W3  + (size_t)k * kC * kC;  const T* b3k  = b3  + (size_t)k * kC;
  const T* W4k  = W4  + (size_t)k * kO * kC;  const T* b4k  = b4  + (size_t)k * kO;

  layer128<T, false, false>(xa,   hres, xa,   W1k,  b1k,  tid); __syncthreads();
  layer128<T, true,  false>(hres, xb,   xa,   Wr1k, br1k, tid); __syncthreads();
  layer128<T, false, true >(xb,   xa,   hres, Wr2k, br2k, tid); __syncthreads();
  layer128<T, true,  false>(xa,   xb,   xa,   W3k,  b3k,  tid); __syncthreads();
  layer_out<T>(xb, W4k, b4k, out, spix, nv, tid);
}

__global__ __launch_bounds__(256, 4) void chain_kernel(
    const void* x, const void* W1, const void* b1, const void* Wr1, const void* br1,
    const void* Wr2, const void* br2, const void* W3, const void* b3,
    const void* W4, const void* b4, void* out, int* wsI) {
  __shared__ unsigned short xa[MT][LDA];    // 8.5 KB each
  __shared__ unsigned short xb[MT][LDA];
  __shared__ unsigned short hres[MT][LDA];
  __shared__ int spix[MT];
  const int* cnt = wsI;
  const int* bucket = wsI + WS_BUCKET;
  if (wsI[4]) {
    chain_body<float>((const float*)x,
                      (const float*)W1, (const float*)b1,
                      (const float*)Wr1, (const float*)br1,
                      (const float*)Wr2, (const float*)br2,
                      (const float*)W3, (const float*)b3,
                      (const float*)W4, (const float*)b4,
                      (float*)out, cnt, bucket, xa, xb, hres, spix);
  } else {
    chain_body<__hip_bfloat16>((const __hip_bfloat16*)x,
                               (const __hip_bfloat16*)W1, (const __hip_bfloat16*)b1,
                               (const __hip_bfloat16*)Wr1, (const __hip_bfloat16*)br1,
                               (const __hip_bfloat16*)Wr2, (const __hip_bfloat16*)br2,
                               (const __hip_bfloat16*)W3, (const __hip_bfloat16*)b3,
                               (const __hip_bfloat16*)W4, (const __hip_bfloat16*)b4,
                               (__hip_bfloat16*)out, cnt, bucket, xa, xb, hres, spix);
  }
}

extern "C" void kernel_launch(void* const* d_in, const int* in_sizes, int n_in,
                              void* d_out, int out_size, void* d_ws, size_t ws_size,
                              hipStream_t stream) {
  (void)in_sizes; (void)n_in; (void)out_size; (void)ws_size;
  int* wsI = (int*)d_ws;   // uses (2048 + NPIX)*4 B ~= 303 KiB
  init_sniff<<<1, 256, 0, stream>>>(d_in[0], d_in[1], wsI);
  count_kernel<<<NBLK, 256, 0, stream>>>(d_in[1], wsI);
  scan_kernel<<<1, 256, 0, stream>>>(wsI);
  place_kernel<<<NBLK, 256, 0, stream>>>(d_in[1], wsI);
  chain_kernel<<<NPIX / MT + kK, 256, 0, stream>>>(
      d_in[0], d_in[2], d_in[3], d_in[4], d_in[5], d_in[6], d_in[7],
      d_in[8], d_in[9], d_in[10], d_in[11], d_out, wsI);
}